// Round 7
// baseline (472.046 us; speedup 1.0000x reference)
//
#include <hip/hip_runtime.h>

typedef __bf16 bf16;
typedef __bf16 bf16x4 __attribute__((ext_vector_type(4)));
typedef __bf16 bf16x8 __attribute__((ext_vector_type(8)));
typedef float f32x4 __attribute__((ext_vector_type(4)));

#define MFMA16(a, b, c) __builtin_amdgcn_mfma_f32_16x16x32_bf16(a, b, c, 0, 0, 0)

// Problem constants: B=8, N=4096, M=256, DIM=256, HEADS=8, DIM_HEAD=64, INNER=512
// exp(S*scale) = exp2(S * 0.125 * log2(e))
#define CEXP 0.18033688011112042f

// async global->LDS, 16B per lane; lds base wave-uniform (HW adds lane*16)
__device__ inline void gload16(const bf16* g, bf16* l) {
  __builtin_amdgcn_global_load_lds(
      (const __attribute__((address_space(1))) unsigned int*)g,
      (__attribute__((address_space(3))) unsigned int*)l, 16, 0, 0);
}

// ---------------------------------------------------------------------------
// Weight pre-transpose + downcast: W[K,N] fp32 -> WT[N,K] bf16 (10 matrices)
// ---------------------------------------------------------------------------
struct WTArgs {
  const float* src[10];
  bf16* dst[10];
  int K[10];
  int N[10];
};

__global__ __launch_bounds__(256) void wtrans_kernel(WTArgs args) {
  const int z = blockIdx.z;
  const int K = args.K[z], N = args.N[z];
  const int k0 = blockIdx.x * 64, n0 = blockIdx.y * 64;
  if (k0 >= K || n0 >= N) return;
  __shared__ float t[64][65];
  const int tx = threadIdx.x & 63, ty = threadIdx.x >> 6;
  const float* __restrict__ src = args.src[z];
  bf16* __restrict__ dst = args.dst[z];
#pragma unroll
  for (int i = 0; i < 16; ++i)
    t[ty + i * 4][tx] = src[(size_t)(k0 + ty + i * 4) * N + n0 + tx];
  __syncthreads();
#pragma unroll
  for (int i = 0; i < 16; ++i)
    dst[(size_t)(n0 + ty + i * 4) * K + k0 + tx] = (bf16)t[tx][ty + i * 4];
}

// ---------------------------------------------------------------------------
// xq[b][n][c] = feat[b][n][c] + pos[b][c][n]  (fp32 in, bf16 out)
// ---------------------------------------------------------------------------
__global__ __launch_bounds__(256) void prep_xq_kernel(
    const float* __restrict__ feat, const float* __restrict__ pos,
    bf16* __restrict__ xq) {
  const int n0 = blockIdx.x * 64;
  const int c0 = blockIdx.y * 64;
  const int b = blockIdx.z;
  __shared__ float t[64][65];
  const int tx = threadIdx.x & 63, ty = threadIdx.x >> 6;
#pragma unroll
  for (int i = 0; i < 16; ++i) {
    int c = ty + i * 4;
    t[c][tx] = pos[((size_t)b * 256 + c0 + c) * 4096 + n0 + tx];
  }
  __syncthreads();
#pragma unroll
  for (int i = 0; i < 16; ++i) {
    int n = ty + i * 4;
    size_t off = ((size_t)b * 4096 + n0 + n) * 256 + c0 + tx;
    xq[off] = (bf16)(feat[off] + t[tx][n]);
  }
}

// xk = center + center_pos (fp32 in, bf16 out, vectorized x4)
__global__ __launch_bounds__(256) void addvec_kernel(
    const float* __restrict__ a, const float* __restrict__ b,
    bf16* __restrict__ o, int n4) {
  int i = blockIdx.x * 256 + threadIdx.x;
  if (i < n4) {
    f32x4 x = ((const f32x4*)a)[i];
    f32x4 y = ((const f32x4*)b)[i];
    bf16x4 z;
#pragma unroll
    for (int j = 0; j < 4; ++j) z[j] = (bf16)(x[j] + y[j]);
    ((bf16x4*)o)[i] = z;
  }
}

// 8 contiguous fp32 -> bf16x8
__device__ inline bf16x8 ldA8f(const float* p) {
  f32x4 u = *(const f32x4*)p;
  f32x4 v = *((const f32x4*)p + 1);
  bf16x8 o;
#pragma unroll
  for (int i = 0; i < 4; ++i) {
    o[i] = (bf16)u[i];
    o[4 + i] = (bf16)v[i];
  }
  return o;
}

// ---------------------------------------------------------------------------
// Generic GEMM: C[M,N] = A[M,K] @ B[K,N], B given as BT[N,K].
// 128x128 tile, 4 waves, BK=32, global_load_lds staging for bf16 operands.
// EPI: 0=none, 1=relu, 2=+resid, 3=+bias+resid.
// ---------------------------------------------------------------------------
template <int EPI, typename TO, typename TR, typename TA, typename TB>
__global__ __launch_bounds__(256) void gemm_kernel(
    const TA* __restrict__ A, const TB* __restrict__ BT,
    TO* __restrict__ C, const TR* __restrict__ resid,
    const float* __restrict__ bias, int M, int N, int K) {
  const int m0 = blockIdx.x * 128;
  const int n0 = blockIdx.y * 128;
  const int tid = threadIdx.x;
  const int lane = tid & 63;
  const int w = tid >> 6;
  const int wr = (w >> 1) * 64, wc = (w & 1) * 64;
  const int l15 = lane & 15, quad = lane >> 4;
  constexpr bool A_BF16 = (sizeof(TA) == 2);
  constexpr bool B_BF16 = (sizeof(TB) == 2);

  __shared__ bf16 Al[128 * 32];
  __shared__ bf16 Bl[128 * 32];

  f32x4 acc[4][4];
#pragma unroll
  for (int i = 0; i < 4; ++i)
#pragma unroll
    for (int j = 0; j < 4; ++j) acc[i][j] = (f32x4){0.f, 0.f, 0.f, 0.f};

  for (int k0 = 0; k0 < K; k0 += 32) {
    if constexpr (B_BF16) {
#pragma unroll
      for (int c = 0; c < 2; ++c) {
        int r0 = w * 32 + c * 16;
        gload16((const bf16*)BT + (size_t)(n0 + r0 + (lane >> 2)) * K + k0 +
                    (lane & 3) * 8,
                Bl + r0 * 32);
      }
    } else {
#pragma unroll
      for (int c = 0; c < 2; ++c) {
        int idx = tid + c * 256;
        int row = idx >> 2;
        int ko = (idx & 3) * 8;
        *(bf16x8*)(Bl + row * 32 + ko) =
            ldA8f((const float*)BT + (size_t)(n0 + row) * K + k0 + ko);
      }
    }
    if constexpr (A_BF16) {
#pragma unroll
      for (int c = 0; c < 2; ++c) {
        int r0 = w * 32 + c * 16;
        gload16((const bf16*)A + (size_t)(m0 + r0 + (lane >> 2)) * K + k0 +
                    (lane & 3) * 8,
                Al + r0 * 32);
      }
    } else {
#pragma unroll
      for (int c = 0; c < 2; ++c) {
        int idx = tid + c * 256;
        int row = idx >> 2;
        int ko = (idx & 3) * 8;
        *(bf16x8*)(Al + row * 32 + ko) =
            ldA8f((const float*)A + (size_t)(m0 + row) * K + k0 + ko);
      }
    }
    __syncthreads();
    bf16x8 fa[4], fb[4];
#pragma unroll
    for (int i = 0; i < 4; ++i) {
      fa[i] = *(const bf16x8*)(Al + (wr + i * 16 + l15) * 32 + quad * 8);
      fb[i] = *(const bf16x8*)(Bl + (wc + i * 16 + l15) * 32 + quad * 8);
    }
#pragma unroll
    for (int i = 0; i < 4; ++i)
#pragma unroll
      for (int j = 0; j < 4; ++j)
        acc[i][j] = MFMA16(fa[i], fb[j], acc[i][j]);
    __syncthreads();
  }

#pragma unroll
  for (int i = 0; i < 4; ++i) {
#pragma unroll
    for (int r = 0; r < 4; ++r) {
      int row = m0 + wr + i * 16 + quad * 4 + r;
      size_t rb = (size_t)row * N + n0 + wc;
#pragma unroll
      for (int j = 0; j < 4; ++j) {
        int col = n0 + wc + j * 16 + l15;
        float v = acc[i][j][r];
        if constexpr (EPI == 1) v = fmaxf(v, 0.f);
        if constexpr (EPI == 2) v += (float)resid[rb + j * 16 + l15];
        if constexpr (EPI == 3)
          v += bias[col] + (float)resid[rb + j * 16 + l15];
        C[rb + j * 16 + l15] = (TO)v;
      }
    }
  }
}

// ---------------------------------------------------------------------------
// attfo1: fused S + softmax-over-m + O1, and ET materialization (per 2-batch
// chunk). Per block (nt of 128 n-rows, h, bl): stage k[256][72] once; loop 4
// m-quarters: stage v2T[64][72] (2 barriers), then per-wave independent:
//   S  = q@k^T tile (MFMA), S^T via swapped MFMA — both C-layout so Pl (per
//   wave) and ET (global) stores are lane-contiguous;
//   O1 += P @ v2T (registers, normalized by in-register rowsum at end) -> af;
//   ET[bh_local][m][n] streamed to global for the o2 GEMM; colsum partials.
// ~11 barriers/block (vs ~96 in the R3/R5 attf). LDS 59.4KB -> 2 blocks/CU.
// af aliases q: each wave reads only its own 16-row stripes of q (its h-slice)
// and writes the same (row,col) set at the end -> safe; q/af not __restrict__.
// ---------------------------------------------------------------------------
__global__ __launch_bounds__(256) void attfo1_kernel(
    const bf16* q, const bf16* __restrict__ kk, const bf16* __restrict__ v2t,
    bf16* af, bf16* __restrict__ ET, float* __restrict__ colp, int b0) {
  const int nt = blockIdx.x;  // 32 tiles of 128 n
  const int h = blockIdx.y;
  const int bl = blockIdx.z;  // 0..1 within chunk
  const int b = b0 + bl;
  const int tid = threadIdx.x;
  const int lane = tid & 63;
  const int w = tid >> 6;
  const int l15 = lane & 15, quad = lane >> 4;

  __shared__ bf16 klds[256 * 72];  // [m][d]
  __shared__ bf16 v2T[64 * 72];    // [d][m_quarter]
  __shared__ bf16 Pl[4][16 * 72];  // per-wave P [n_stripe][m_quarter]
  __shared__ float csld[4][256];

  // stage full k slice [256 m][64 d] (barrier inside first mq iteration)
#pragma unroll
  for (int c = 0; c < 8; ++c) {
    int idx = tid + c * 256;
    int m = idx >> 3, dc = (idx & 7) * 8;
    *(bf16x8*)(klds + m * 72 + dc) =
        *(const bf16x8*)(kk + ((size_t)(b * 256 + m)) * 512 + h * 64 + dc);
  }

  const bf16* v2b = v2t + (size_t)(h * 64) * 2048 + b * 256;  // [d][m]
  bf16* ETb = ET + (size_t)(bl * 8 + h) * 256 * 4096;

  f32x4 oacc[2][4];
#pragma unroll
  for (int i = 0; i < 2; ++i)
#pragma unroll
    for (int j = 0; j < 4; ++j) oacc[i][j] = (f32x4){0.f, 0.f, 0.f, 0.f};
  float rs[2][4] = {{0.f, 0.f, 0.f, 0.f}, {0.f, 0.f, 0.f, 0.f}};
  float cs[16];
#pragma unroll
  for (int i = 0; i < 16; ++i) cs[i] = 0.f;

  for (int mq = 0; mq < 4; ++mq) {
    __syncthreads();  // WAR on v2T (first iter: also k staging fence)
    // stage v2T quarter [64 d][64 m]
#pragma unroll
    for (int c = 0; c < 2; ++c) {
      int idx = tid + c * 256;
      int d = idx >> 3, mc = (idx & 7) * 8;
      *(bf16x8*)(v2T + d * 72 + mc) =
          *(const bf16x8*)(v2b + (size_t)d * 2048 + mq * 64 + mc);
    }
    __syncthreads();

#pragma unroll
    for (int it = 0; it < 2; ++it) {
      const int nl = nt * 128 + it * 64 + w * 16;
      const bf16* qp =
          q + ((size_t)(b * 4096 + nl + l15)) * 512 + h * 64 + quad * 8;
      bf16x8 a0 = *(const bf16x8*)qp;
      bf16x8 a1 = *(const bf16x8*)(qp + 32);

#pragma unroll
      for (int mt = 0; mt < 4; ++mt) {
        const bf16* kp = klds + (mq * 64 + mt * 16 + l15) * 72 + quad * 8;
        bf16x8 b0 = *(const bf16x8*)kp;
        bf16x8 b1 = *(const bf16x8*)(kp + 32);
        f32x4 s = (f32x4){0.f, 0.f, 0.f, 0.f};
        s = MFMA16(a0, b0, s);  // S[n][m], col m = l15
        s = MFMA16(a1, b1, s);
        f32x4 st = (f32x4){0.f, 0.f, 0.f, 0.f};
        st = MFMA16(b0, a0, st);  // S^T[m][n], col n = l15
        st = MFMA16(b1, a1, st);
#pragma unroll
        for (int r = 0; r < 4; ++r) {
          float e = exp2f(s[r] * CEXP);
          rs[it][r] += e;
          cs[mq * 4 + mt] += e;
          Pl[w][(quad * 4 + r) * 72 + mt * 16 + l15] = (bf16)e;
          ETb[(size_t)(mq * 64 + mt * 16 + quad * 4 + r) * 4096 + nl + l15] =
              (bf16)exp2f(st[r] * CEXP);
        }
      }
      asm volatile("" ::: "memory");  // order Pl stores before vector reloads
      // O1 += P @ v2T quarter (K=64 -> 2 ksteps)
#pragma unroll
      for (int ks = 0; ks < 2; ++ks) {
        bf16x8 pa = *(const bf16x8*)(Pl[w] + l15 * 72 + ks * 32 + quad * 8);
#pragma unroll
        for (int dt = 0; dt < 4; ++dt) {
          bf16x8 vb =
              *(const bf16x8*)(v2T + (dt * 16 + l15) * 72 + ks * 32 + quad * 8);
          oacc[it][dt] = MFMA16(pa, vb, oacc[it][dt]);
        }
      }
      asm volatile("" ::: "memory");  // order reads before next iter's stores
    }
  }

  // normalize rows and write af (aliases q; wave-private rows)
#pragma unroll
  for (int it = 0; it < 2; ++it) {
    float inv[4];
#pragma unroll
    for (int r = 0; r < 4; ++r) {
      float v = rs[it][r];
      v += __shfl_xor(v, 1, 64);
      v += __shfl_xor(v, 2, 64);
      v += __shfl_xor(v, 4, 64);
      v += __shfl_xor(v, 8, 64);
      inv[r] = 1.f / v;
    }
#pragma unroll
    for (int dt = 0; dt < 4; ++dt) {
#pragma unroll
      for (int r = 0; r < 4; ++r) {
        int n = nt * 128 + it * 64 + w * 16 + quad * 4 + r;
        af[((size_t)(b * 4096 + n)) * 512 + h * 64 + dt * 16 + l15] =
            (bf16)(oacc[it][dt][r] * inv[r]);
      }
    }
  }

  // colsum partials: reduce over quads, then across waves via LDS
#pragma unroll
  for (int t = 0; t < 16; ++t) {
    float v = cs[t];
    v += __shfl_xor(v, 16, 64);
    v += __shfl_xor(v, 32, 64);
    if (quad == 0) csld[w][(t >> 2) * 64 + (t & 3) * 16 + l15] = v;
  }
  __syncthreads();
  {
    float v = csld[0][tid] + csld[1][tid] + csld[2][tid] + csld[3][tid];
    colp[((size_t)nt * 64 + b * 8 + h) * 256 + tid] = v;
  }
}

// colsum[bh][m] = sum over 32 n-tile partials
__global__ __launch_bounds__(256) void colred_kernel(
    const float* __restrict__ colp, float* __restrict__ colsum) {
  int i = blockIdx.x * 256 + threadIdx.x;  // bh*256+m, 16384 total
  float v = 0.f;
#pragma unroll
  for (int p = 0; p < 32; ++p) v += colp[(size_t)p * 16384 + i];
  colsum[i] = v;
}

// ---------------------------------------------------------------------------
// o2: o2p[ks][bhg][m][d] = ET[bhl][mt*64..][ks*512..+512] @ v1t[d][...]
// Tile 64m x 64d, 4 waves (16x64 each), K=512 per split, BK=32.
// ---------------------------------------------------------------------------
__global__ __launch_bounds__(256) void o2_kernel(
    const bf16* __restrict__ ET, const bf16* __restrict__ v1t,
    float* __restrict__ o2p, int b0) {
  const int mt = blockIdx.x;   // 4
  const int ks = blockIdx.y;   // 8
  const int bhl = blockIdx.z;  // 16 (chunk-local bh)
  const int bl = bhl >> 3, h = bhl & 7;
  const int b = b0 + bl;
  const int bhg = b * 8 + h;
  const int tid = threadIdx.x;
  const int lane = tid & 63;
  const int w = tid >> 6;
  const int l15 = lane & 15, quad = lane >> 4;

  __shared__ bf16 Al[64 * 32];
  __shared__ bf16 Bl[64 * 32];

  const bf16* Ab =
      ET + (size_t)bhl * 256 * 4096 + (size_t)mt * 64 * 4096 + ks * 512;
  const bf16* Bb = v1t + (size_t)(h * 64) * 32768 + b * 4096 + ks * 512;

  f32x4 acc[4];
#pragma unroll
  for (int j = 0; j < 4; ++j) acc[j] = (f32x4){0.f, 0.f, 0.f, 0.f};

  for (int k0 = 0; k0 < 512; k0 += 32) {
    gload16(Ab + (size_t)(w * 16 + (lane >> 2)) * 4096 + k0 + (lane & 3) * 8,
            Al + w * 16 * 32);
    gload16(Bb + (size_t)(w * 16 + (lane >> 2)) * 32768 + k0 + (lane & 3) * 8,
            Bl + w * 16 * 32);
    __syncthreads();
    bf16x8 fa = *(const bf16x8*)(Al + (w * 16 + l15) * 32 + quad * 8);
#pragma unroll
    for (int j = 0; j < 4; ++j) {
      bf16x8 fb = *(const bf16x8*)(Bl + (j * 16 + l15) * 32 + quad * 8);
      acc[j] = MFMA16(fa, fb, acc[j]);
    }
    __syncthreads();
  }

  float* ob = o2p + ((size_t)ks * 64 + bhg) * 16384 + (size_t)(mt * 64) * 64;
#pragma unroll
  for (int j = 0; j < 4; ++j)
#pragma unroll
    for (int r = 0; r < 4; ++r)
      ob[(w * 16 + quad * 4 + r) * 64 + j * 16 + l15] = acc[j][r];
}

// acm[b][m][h*64+d] = (sum_ks o2p) / colsum[bh][m]
__global__ __launch_bounds__(256) void acmr_kernel(
    const float* __restrict__ o2p, const float* __restrict__ colsum,
    bf16* __restrict__ acm) {
  int idx = blockIdx.x * 256 + threadIdx.x;  // [b][m][h][d]
  int d = idx & 63;
  int h = (idx >> 6) & 7;
  int m = (idx >> 9) & 255;
  int b = idx >> 17;
  int bh = b * 8 + h;
  size_t base = ((size_t)bh * 256 + m) * 64 + d;
  float v = 0.f;
#pragma unroll
  for (int p = 0; p < 8; ++p) v += o2p[base + (size_t)p * 1048576];
  acm[idx] = (bf16)(v / colsum[bh * 256 + m]);
}

// ---------------------------------------------------------------------------
// LayerNorm over last dim (256): one wave per row, 4 rows per block.
// ---------------------------------------------------------------------------
__global__ __launch_bounds__(256) void ln_kernel(
    const bf16* __restrict__ x, const float* __restrict__ wv,
    const float* __restrict__ bv, bf16* __restrict__ y, int rows) {
  int wave = threadIdx.x >> 6;
  int lane = threadIdx.x & 63;
  int row = blockIdx.x * 4 + wave;
  if (row >= rows) return;
  const bf16* xr = x + (size_t)row * 256;
  bf16x4 v = *(const bf16x4*)(xr + lane * 4);
  float f0 = v[0], f1 = v[1], f2 = v[2], f3 = v[3];
  float s = f0 + f1 + f2 + f3;
  float ss = f0 * f0 + f1 * f1 + f2 * f2 + f3 * f3;
#pragma unroll
  for (int m = 1; m < 64; m <<= 1) {
    s += __shfl_xor(s, m, 64);
    ss += __shfl_xor(ss, m, 64);
  }
  float mean = s * (1.f / 256.f);
  float var = ss * (1.f / 256.f) - mean * mean;
  float rstd = rsqrtf(var + 1e-5f);
  f32x4 wq = *(const f32x4*)(wv + lane * 4);
  f32x4 bq = *(const f32x4*)(bv + lane * 4);
  bf16x4 o;
  o[0] = (bf16)((f0 - mean) * rstd * wq[0] + bq[0]);
  o[1] = (bf16)((f1 - mean) * rstd * wq[1] + bq[1]);
  o[2] = (bf16)((f2 - mean) * rstd * wq[2] + bq[2]);
  o[3] = (bf16)((f3 - mean) * rstd * wq[3] + bq[3]);
  *(bf16x4*)(y + (size_t)row * 256 + lane * 4) = o;
}

// ---------------------------------------------------------------------------
extern "C" void kernel_launch(void* const* d_in, const int* in_sizes, int n_in,
                              void* d_out, int out_size, void* d_ws,
                              size_t ws_size, hipStream_t stream) {
  const float* feat = (const float*)d_in[0];
  const float* center = (const float*)d_in[1];
  const float* pos = (const float*)d_in[2];
  const float* cpos = (const float*)d_in[3];
  const float* Wq = (const float*)d_in[4];
  const float* Wk = (const float*)d_in[5];
  const float* Wv1 = (const float*)d_in[6];
  const float* Wv2 = (const float*)d_in[7];
  const float* Wo1 = (const float*)d_in[8];
  const float* Wo2 = (const float*)d_in[9];
  const float* ln1w = (const float*)d_in[10];
  const float* ln1b = (const float*)d_in[11];
  const float* ln2w = (const float*)d_in[12];
  const float* ln2b = (const float*)d_in[13];
  const float* f1W1 = (const float*)d_in[14];
  const float* f1W2 = (const float*)d_in[15];
  const float* f1b2 = (const float*)d_in[16];
  const float* f2W1 = (const float*)d_in[17];
  const float* f2W2 = (const float*)d_in[18];
  const float* f2b2 = (const float*)d_in[19];

  char* ws = (char*)d_ws;
  const size_t MB = 1024 * 1024;
  // workspace layout — PEAK 107 MB (ET sized correctly this time: per-chunk
  // [16bh][256][4096] bf16 = 32MB, overlaid on dead xq region):
  bf16* q_ = (bf16*)(ws + 0);          // 32MB [32768,512]; af aliases q
  bf16* af_ = q_;
  bf16* v1t_ = (bf16*)(ws + 32 * MB);  // 32MB [512,32768]
  bf16* k_ = (bf16*)(ws + 64 * MB);    // 2MB [2048,512]
  bf16* v2t_ = (bf16*)(ws + 66 * MB);  // 2MB [512,2048]; acm after attention
  bf16* acm_ = v2t_;
  bf16* wt_ = (bf16*)(ws + 68 * MB);   // 2MB transposed weights
  float* colp_ = (float*)(ws + 70 * MB);    // 2MB fp32 [32][64][256]
  float* colsum_ = (float*)(ws + 72 * MB);  // 64KB fp32 [64][256]
  bf16* xk_ = (bf16*)(ws + 72 * MB + 65536);  // 1MB; rc after
  bf16* rc_ = xk_;
  bf16* xq_ = (bf16*)(ws + 73 * MB);   // 16MB (dead after q GEMM)
  bf16* ET_ = (bf16*)(ws + 73 * MB);   // 32MB per-chunk (73-105MB)
  bf16* rf_ = (bf16*)(ws + 73 * MB);   // 16MB (post-attention, over dead ET)
  bf16* tf_ = (bf16*)(ws + 89 * MB);   // 16MB (post-LN, over dead ET)
  bf16* yf_ = q_;                      // af dead after Wo1 GEMM
  bf16* yc_ = (bf16*)(ws + 105 * MB);  // 1MB
  bf16* tc_ = (bf16*)(ws + 106 * MB);  // 1MB

  // o2 partials in d_out: [8ks][64bh][256][64] fp32 = 32MB, inside the
  // 33.5MB out_feat region; fully overwritten by the final feat GEMM.
  float* out_feat = (float*)d_out;
  float* out_center = out_feat + (size_t)8 * 4096 * 256;
  float* o2p_ = out_feat;

  bf16* WqT = wt_;
  bf16* WkT = WqT + 131072;
  bf16* Wv1T = WkT + 131072;
  bf16* Wv2T = Wv1T + 131072;
  bf16* Wo1T = Wv2T + 131072;
  bf16* Wo2T = Wo1T + 131072;
  bf16* f1W1T = Wo2T + 131072;
  bf16* f1W2T = f1W1T + 65536;
  bf16* f2W1T = f1W2T + 65536;
  bf16* f2W2T = f2W1T + 65536;

  WTArgs wa;
  const float* srcs[10] = {Wq, Wk, Wv1, Wv2, Wo1, Wo2, f1W1, f1W2, f2W1, f2W2};
  bf16* dsts[10] = {WqT, WkT, Wv1T, Wv2T, Wo1T, Wo2T, f1W1T, f1W2T, f2W1T, f2W2T};
  int Ks[10] = {256, 256, 256, 256, 512, 512, 256, 256, 256, 256};
  int Ns[10] = {512, 512, 512, 512, 256, 256, 256, 256, 256, 256};
  for (int i = 0; i < 10; ++i) {
    wa.src[i] = srcs[i];
    wa.dst[i] = dsts[i];
    wa.K[i] = Ks[i];
    wa.N[i] = Ns[i];
  }

  wtrans_kernel<<<dim3(8, 8, 10), 256, 0, stream>>>(wa);
  prep_xq_kernel<<<dim3(64, 4, 8), 256, 0, stream>>>(feat, pos, xq_);
  addvec_kernel<<<dim3(512), 256, 0, stream>>>(center, cpos, xk_, 131072);

  // projections; v1t/v2t transposed via swapped GEMM (C^T = B^T @ A^T)
  gemm_kernel<0, bf16, bf16, bf16, bf16><<<dim3(256, 4), 256, 0, stream>>>(
      xq_, WqT, q_, nullptr, nullptr, 32768, 512, 256);
  gemm_kernel<0, bf16, bf16, bf16, bf16><<<dim3(16, 4), 256, 0, stream>>>(
      xk_, WkT, k_, nullptr, nullptr, 2048, 512, 256);
  gemm_kernel<0, bf16, bf16, bf16, float><<<dim3(4, 256), 256, 0, stream>>>(
      Wv1T, feat, v1t_, nullptr, nullptr, 512, 32768, 256);
  gemm_kernel<0, bf16, bf16, bf16, float><<<dim3(4, 16), 256, 0, stream>>>(
      Wv2T, center, v2t_, nullptr, nullptr, 512, 2048, 256);

  // attention: 4 chunks of 2 batches (ET buffer reused per chunk)
  for (int c = 0; c < 4; ++c) {
    attfo1_kernel<<<dim3(32, 8, 2), 256, 0, stream>>>(q_, k_, v2t_, af_, ET_,
                                                      colp_, c * 2);
    o2_kernel<<<dim3(4, 8, 16), 256, 0, stream>>>(ET_, v1t_, o2p_, c * 2);
  }
  colred_kernel<<<dim3(64), 256, 0, stream>>>(colp_, colsum_);
  acmr_kernel<<<dim3(4096), 256, 0, stream>>>(o2p_, colsum_, acm_);

  // feat path
  gemm_kernel<2, bf16, float, bf16, bf16><<<dim3(256, 2), 256, 0, stream>>>(
      af_, Wo1T, rf_, feat, nullptr, 32768, 256, 512);
  ln_kernel<<<dim3(8192), 256, 0, stream>>>(rf_, ln1w, ln1b, yf_, 32768);
  gemm_kernel<1, bf16, bf16, bf16, bf16><<<dim3(256, 2), 256, 0, stream>>>(
      yf_, f1W1T, tf_, nullptr, nullptr, 32768, 256, 256);
  gemm_kernel<3, float, bf16, bf16, bf16><<<dim3(256, 2), 256, 0, stream>>>(
      tf_, f1W2T, out_feat, yf_, f1b2, 32768, 256, 256);

  // center path
  gemm_kernel<2, bf16, float, bf16, bf16><<<dim3(16, 2), 256, 0, stream>>>(
      acm_, Wo2T, rc_, center, nullptr, 2048, 256, 512);
  ln_kernel<<<dim3(512), 256, 0, stream>>>(rc_, ln2w, ln2b, yc_, 2048);
  gemm_kernel<1, bf16, bf16, bf16, bf16><<<dim3(16, 2), 256, 0, stream>>>(
      yc_, f2W1T, tc_, nullptr, nullptr, 2048, 256, 256);
  gemm_kernel<3, float, bf16, bf16, bf16><<<dim3(16, 2), 256, 0, stream>>>(
      tc_, f2W2T, out_center, yc_, f2b2, 2048, 256, 256);
}